// Round 12
// baseline (59.909 us; speedup 1.0000x reference)
//
#include <hip/hip_runtime.h>
#include <math.h>
#include <utility>

#define EPSF 1e-12f

constexpr int LLEN = 1024;
constexpr int WMAX = 60;
constexpr int LP   = 964;
constexpr int NF   = 158;
constexpr int CHUNK = 64;
constexpr int SPAN  = CHUNK + WMAX; // 124
constexpr int NCH   = (LP + CHUNK - 1) / CHUNK; // 16
constexpr int OBW   = 87;           // LDS row stride; 87%32=23 coprime w/ 32
constexpr int PH1   = 71;           // phase-1 width: base(13)+w5(29)+w10(29)
constexpr int NT    = 320;          // 5 waves: A0 C0 A1 C1 B
constexpr int NW    = 5;

__device__ __forceinline__ float frcp(float x) {
#if __has_builtin(__builtin_amdgcn_rcpf)
  return __builtin_amdgcn_rcpf(x);
#else
  return 1.0f / x;
#endif
}

template<int I0, class F, int... Is>
__device__ __forceinline__ void unroll_impl(F&& f, std::integer_sequence<int, Is...>) {
  (f(std::integral_constant<int, I0 + Is>{}), ...);
}
template<int I0, int N, class F>
__device__ __forceinline__ void unroll_for(F&& f) {
  unroll_impl<I0>(f, std::make_integer_sequence<int, N>{});
}

template<int N>
__device__ __forceinline__ void bitonic_sort(float (&a)[N]) {
#pragma unroll
  for (int k = 2; k <= N; k <<= 1) {
#pragma unroll
    for (int j = k >> 1; j > 0; j >>= 1) {
#pragma unroll
      for (int i = 0; i < N; ++i) {
        int l = i ^ j;
        if (l > i) {
          float x = a[i], y = a[l];
          float mn = fminf(x, y), mx = fmaxf(x, y);
          if ((i & k) == 0) { a[i] = mn; a[l] = mx; }
          else              { a[i] = mx; a[l] = mn; }
        }
      }
    }
  }
}

// Ascending merge of a bitonic sequence (asc half ++ desc half).
template<int N>
__device__ __forceinline__ void bitonic_merge(float (&a)[N]) {
#pragma unroll
  for (int j = N >> 1; j > 0; j >>= 1) {
#pragma unroll
    for (int i = 0; i < N; ++i) {
      int l = i ^ j;
      if (l > i) {
        float x = a[i], y = a[l];
        a[i] = fminf(x, y); a[l] = fmaxf(x, y);
      }
    }
  }
}

// pass1 feature emit (slots 0-7,10-15,23,24); c_ is close[T-W_].
#define EMITA(W_, FI_) do {                                                   \
  constexpr float wf_  = (float)(W_);                                         \
  constexpr float inw_ = 1.0f / wf_;                                          \
  constexpr float tm_  = (W_ - 1) * 0.5f;                                     \
  constexpr float tv_  = (float)(((double)(W_) * (W_) - 1.0) / 12.0);         \
  float scm_  = sc * inw_;                                                    \
  float ym_   = cl + scm_;                                                    \
  float yvar_ = fmaxf(sc2 * inw_ - scm_ * scm_, 0.f);                         \
  float stdv_ = sqrtf(yvar_);                                                 \
  float skc_  = (wf_ - 1.f) * sc - sic;                                       \
  float cov_  = skc_ * inw_ - tm_ * scm_;                                     \
  float slope_ = cov_ * (1.0f / tv_);                                         \
  float rsqr_  = cov_ * cov_ * frcp(tv_ * yvar_ + EPSF);                      \
  float resi_  = (cl - ym_) - slope_ * tm_;                                   \
  float cnum_ = sclg - sc * slg * inw_;                                       \
  float cden_ = sqrtf(fmaxf(sc2 - sc * sc * inw_, 0.f) *                      \
                      fmaxf(slg2 - slg * slg * inw_, 0.f)) + EPSF;            \
  float corr_ = cnum_ * frcp(cden_);                                          \
  float vmean_ = sv * inw_;                                                   \
  float vvar_  = fmaxf(sv2 * inw_ - vmean_ * vmean_, 0.f);                    \
  float imaxf_ = (float)((W_ - 1) - imax) * inw_;                             \
  float iminf_ = (float)((W_ - 1) - imin) * inw_;                             \
  outr[FI_ + 0]  = c_ * rcl;                                                  \
  outr[FI_ + 1]  = ym_ * rcl;                                                 \
  outr[FI_ + 2]  = stdv_ * rcl;                                               \
  outr[FI_ + 3]  = slope_ * rcl;                                              \
  outr[FI_ + 4]  = rsqr_;                                                     \
  outr[FI_ + 5]  = resi_ * rcl;                                               \
  outr[FI_ + 6]  = hmax * rcl;                                                \
  outr[FI_ + 7]  = lmin * rcl;                                                \
  outr[FI_ + 10] = (float)cntle * inw_;                                       \
  outr[FI_ + 11] = (cl - lmin) * frcp(hmax - lmin + EPSF);                    \
  outr[FI_ + 12] = imaxf_;                                                    \
  outr[FI_ + 13] = iminf_;                                                    \
  outr[FI_ + 14] = imaxf_ - iminf_;                                           \
  outr[FI_ + 23] = vmean_ * rvA;                                              \
  outr[FI_ + 24] = sqrtf(vvar_) * rvA;                                        \
  outr[FI_ + 15] = corr_;                                                     \
} while (0)

// pass2 feature emit (slots 16-22,25-28).
#define EMITC(W_, FI_) do {                                                   \
  constexpr float inw_ = 1.0f / (float)(W_);                                  \
  float dnum_ = srl - sr * sl * inw_;                                         \
  float dden_ = sqrtf(fmaxf(sr2 - sr * sr * inw_, 0.f) *                      \
                      fmaxf(sl2 - sl * sl * inw_, 0.f)) + EPSF;               \
  float cord_ = dnum_ * frcp(dden_);                                          \
  float ra_ = frcp(sp + sn + EPSF);                                           \
  float sump_ = sp * ra_,  sumn_ = sn * ra_;                                  \
  float rv_ = frcp(dvp + dvn + EPSF);                                         \
  float vsump_ = dvp * rv_, vsumn_ = dvn * rv_;                               \
  float wmean_ = sw * inw_;                                                   \
  float wvar_  = fmaxf(sw2 * inw_ - wmean_ * wmean_, 0.f);                    \
  float cntp_ = (float)npos * inw_, cntn_ = (float)nneg * inw_;               \
  outr[FI_ + 16] = cord_;                                                     \
  outr[FI_ + 17] = cntp_;                                                     \
  outr[FI_ + 18] = cntn_;                                                     \
  outr[FI_ + 19] = cntp_ - cntn_;                                             \
  outr[FI_ + 20] = sump_;                                                     \
  outr[FI_ + 21] = sumn_;                                                     \
  outr[FI_ + 22] = sump_ - sumn_;                                             \
  outr[FI_ + 25] = sqrtf(wvar_) * frcp(wmean_ + EPSF);                        \
  outr[FI_ + 26] = vsump_;                                                    \
  outr[FI_ + 27] = vsumn_;                                                    \
  outr[FI_ + 28] = vsump_ - vsumn_;                                           \
} while (0)

// quantile emit from sorted array (jnp.quantile 'linear').
#define QEMIT(W_, FI_, TA_) do {                                              \
  constexpr int   k8_  = (int)(0.8 * (W_ - 1));                               \
  constexpr float f8_  = (float)(0.8 * (W_ - 1) - k8_);                       \
  constexpr int   k2_  = (int)(0.2 * (W_ - 1));                               \
  constexpr float f2_  = (float)(0.2 * (W_ - 1) - k2_);                       \
  outr[FI_ + 8] = (TA_[k8_] + f8_ * (TA_[k8_ + 1] - TA_[k8_])) * rcl;         \
  outr[FI_ + 9] = (TA_[k2_] + f2_ * (TA_[k2_ + 1] - TA_[k2_])) * rcl;         \
} while (0)

__global__ __launch_bounds__(NT, 4)
void factor_kernel(const float* __restrict__ x, float* __restrict__ out, int B)
{
  __shared__ float cs[SPAN], hs[SPAN], ls[SPAN], vs[SPAN], lgs[SPAN]; // 2480 B
  __shared__ float ob[CHUNK * OBW];     // 22272 B
  __shared__ float s30l[CHUNK * 31];    // 7936 B  (B's sorted low-half)
  __shared__ float parts[CHUNK * 26];   // 6656 B  (A1: 0..12, C1: 13..25)

  const int b    = blockIdx.x / NCH;
  const int ch   = blockIdx.x % NCH;
  const int t0   = WMAX + ch * CHUNK;
  const int clen = min(CHUNK, LP - ch * CHUNK);
  const int base = t0 - WMAX;
  const int span = clen + WMAX;
  const int tid  = threadIdx.x;
  const int tt   = tid & 63;
  const int role = tid >> 6;   // 0=A0 1=C0 2=A1 3=C1 4=B

  for (int u = tid; u < span; u += NT) {
    const float* p = x + (size_t)(b * LLEN + base + u) * 6;
    float hv = p[1], lv = p[2], cv = p[3], vv = p[4];
    cs[u] = cv; hs[u] = hv; ls[u] = lv; vs[u] = vv;
    lgs[u] = logf(vv + 1.f);
  }
  __syncthreads();

  const bool active = (tt < clen);
  const int tg = t0 + tt;

  const float* cb = cs  + tt;    // cb[WMAX - i] == series[T - i]
  const float* hb = hs  + tt;
  const float* lb = ls  + tt;
  const float* vb = vs  + tt;
  const float* gb = lgs + tt;

  const float cl  = cb[WMAX];
  const float vol = vb[WMAX];
  const float lgT = gb[WMAX];
  const float rcl = 1.0f / cl;
  const float rvA = 1.0f / (vol + EPSF);

  float* outr = ob + tt * OBW;
  float* s30r = s30l + tt * 31;
  float* pp   = parts + tt * 26;

  // scan state (role-specific subsets; persists across barriers)
  float sc = 0.f, sc2 = 0.f, sic = 0.f;
  float sv = 0.f, sv2 = 0.f;
  float slg = 0.f, slg2 = 0.f, sclg = 0.f;
  int   cntle = 0;
  float hmax = -INFINITY, lmin = INFINITY;
  int   imax = 0, imin = 0;
  float sr = 0.f, sr2 = 0.f, sl = 0.f, sl2 = 0.f, srl = 0.f;
  float sw = 0.f, sw2 = 0.f;
  float sp = 0.f, sn = 0.f, dvp = 0.f, dvn = 0.f;
  int   npos = 0, nneg = 0;
  float pv_c = 0.f, pv_v = 0.f;
  float c_ = 0.f, h_ = 0.f, l_ = 0.f, v_ = 0.f, lg_ = 0.f;

  auto loadA = [&](auto ic) {
    constexpr int i = decltype(ic)::value;
    constexpr int q = WMAX - i;
    c_ = cb[q];
    if constexpr (i < WMAX) { h_ = hb[q]; l_ = lb[q]; v_ = vb[q]; lg_ = gb[q]; }
  };
  auto p1A = [&](auto ic) {
    constexpr int i = decltype(ic)::value;
    float cd = c_ - cl;
    sc += cd; sc2 = fmaf(cd, cd, sc2); sic = fmaf((float)i, cd, sic);
    cntle += (c_ <= cl) ? 1 : 0;
    if (h_ >= hmax) { hmax = h_; imax = i; }
    if (l_ <= lmin) { lmin = l_; imin = i; }
    sv += v_; sv2 = fmaf(v_, v_, sv2);
    float ld = lg_ - lgT;
    slg += ld; slg2 = fmaf(ld, ld, slg2); sclg = fmaf(cd, ld, sclg);
  };
  auto stepA = [&](auto ic) { loadA(ic); p1A(ic); };

  auto pairC = [&](auto ic) {
    constexpr int i = decltype(ic)::value;
    constexpr int q = WMAX - i;
    c_ = cb[q]; v_ = vb[q];
    if constexpr (i >= 1) {
      float d   = pv_c - c_;
      float dv  = pv_v - v_;
      float r   = pv_c * frcp(c_) - 1.f;
      float lcv = __logf(pv_v * frcp(v_ + EPSF) + 1.f);
      float wvv = fabsf(r) * pv_v;
      sr += r;   sr2 = fmaf(r, r, sr2);
      sl += lcv; sl2 = fmaf(lcv, lcv, sl2); srl = fmaf(r, lcv, srl);
      sw += wvv; sw2 = fmaf(wvv, wvv, sw2);
      npos += (d > 0.f) ? 1 : 0;
      nneg += (d < 0.f) ? 1 : 0;
      sp  += fmaxf(d, 0.f);  sn  += fmaxf(-d, 0.f);
      dvp += fmaxf(dv, 0.f); dvn += fmaxf(-dv, 0.f);
    }
  };
  auto stepC = [&](auto ic) { pairC(ic); pv_c = c_; pv_v = v_; };

  // ================= phase 1 (features 0..70) =================
  if (active) {
    if (role == 0) {                               // A0: base + pass1 i=0..10
      const float* p = x + (size_t)(b * LLEN + tg) * 6;
      float opn = p[0], vwp = p[5];
      float hi = hb[WMAX], lo = lb[WMAX];
      float hl = hi - lo + EPSF;
      float rhl = frcp(hl);
      float ro  = 1.0f / opn;
      float mx_oc = fmaxf(opn, cl), mn_oc = fminf(opn, cl);
      float body2 = 2.f * cl - hi - lo;
      outr[0]  = (cl - opn) * ro;
      outr[1]  = (hi - lo) * ro;
      outr[2]  = (cl - opn) * rhl;
      outr[3]  = (hi - mx_oc) * ro;
      outr[4]  = (hi - mx_oc) * rhl;
      outr[5]  = (mn_oc - lo) * ro;
      outr[6]  = (mn_oc - lo) * rhl;
      outr[7]  = body2 * ro;
      outr[8]  = body2 * rhl;
      outr[9]  = opn * rcl;
      outr[10] = hi * rcl;
      outr[11] = lo * rcl;
      outr[12] = vwp * rcl;

      unroll_for<0, 5>(stepA);                     // i = 0..4
      loadA(std::integral_constant<int, 5>{});
      EMITA(5, 13);
      p1A(std::integral_constant<int, 5>{});
      unroll_for<6, 4>(stepA);                     // i = 6..9
      loadA(std::integral_constant<int, 10>{});
      EMITA(10, 42);
      p1A(std::integral_constant<int, 10>{});
    } else if (role == 1) {                        // C0: pass2 pairs 1..10
      unroll_for<0, 5>(stepC);
      pairC(std::integral_constant<int, 5>{});
      EMITC(5, 13);
      pv_c = c_; pv_v = v_;
      unroll_for<6, 4>(stepC);
      pairC(std::integral_constant<int, 10>{});
      EMITC(10, 42);
      pv_c = c_; pv_v = v_;
    } else if (role == 2) {                        // A1: pass1 i=30..59 -> partials
      unroll_for<30, 30>(stepA);
      pp[0] = sc;  pp[1] = sc2; pp[2] = sic;
      pp[3] = sv;  pp[4] = sv2;
      pp[5] = slg; pp[6] = slg2; pp[7] = sclg;
      pp[8] = hmax; pp[9] = lmin;
      pp[10] = (float)cntle; pp[11] = (float)imax; pp[12] = (float)imin;
    } else if (role == 3) {                        // C1: pass2 pairs 31..60 -> partials
      c_ = cb[WMAX - 30]; v_ = vb[WMAX - 30];
      pv_c = c_; pv_v = v_;
      unroll_for<31, 29>(stepC);
      pairC(std::integral_constant<int, 60>{});
      pp[13] = sr;  pp[14] = sr2;
      pp[15] = sl;  pp[16] = sl2; pp[17] = srl;
      pp[18] = sw;  pp[19] = sw2;
      pp[20] = sp;  pp[21] = sn;
      pp[22] = dvp; pp[23] = dvn;
      pp[24] = (float)npos; pp[25] = (float)nneg;
    } else {                                       // B: q5, q10, s30 sort -> LDS
      float t8[8];
      unroll_for<0, 8>([&](auto qi) {
        constexpr int i = decltype(qi)::value;
        t8[i] = (i < 5) ? cb[WMAX - i] : INFINITY;
      });
      bitonic_sort<8>(t8);
      QEMIT(5, 13, t8);
      float t16[16];
      unroll_for<0, 16>([&](auto qi) {
        constexpr int i = decltype(qi)::value;
        t16[i] = (i < 10) ? cb[WMAX - i] : INFINITY;
      });
      bitonic_sort<16>(t16);
      QEMIT(10, 42, t16);
      float s30[32];
      unroll_for<0, 32>([&](auto qi) {
        constexpr int i = decltype(qi)::value;
        s30[i] = (i < 30) ? cb[WMAX - i] : INFINITY;
      });
      bitonic_sort<32>(s30);
      unroll_for<0, 30>([&](auto qi) {
        constexpr int i = decltype(qi)::value;
        s30r[i] = s30[i];
      });
    }
  }
  __syncthreads();

  { // flush 1: features 0..70 (division-free: wave=row, lane=col)
    float* gout = out + ((size_t)b * LP + ch * CHUNK) * NF;
    for (int r = role; r < clen; r += NW) {
      const float* src = ob + r * OBW;
      float* dst = gout + (size_t)r * NF;
      for (int k = tt; k < PH1; k += 64) dst[k] = src[k];
    }
  }
  __syncthreads();

  // ================= phase 2 (features 71..157) =================
  if (active) {
    if (role == 0) {                               // A0: i=11..29, emits w20,w30; combine; w60
      unroll_for<11, 9>(stepA);
      loadA(std::integral_constant<int, 20>{});
      EMITA(20, 0);                                // global 71..99
      p1A(std::integral_constant<int, 20>{});
      unroll_for<21, 9>(stepA);
      loadA(std::integral_constant<int, 30>{});
      EMITA(30, 29);                               // global 100..128
      // combine A1's i=30..59 partials (covers i=30 onward; do NOT add i=30 here)
      sc += pp[0]; sc2 += pp[1]; sic += pp[2];
      sv += pp[3]; sv2 += pp[4];
      slg += pp[5]; slg2 += pp[6]; sclg += pp[7];
      {
        float hD = pp[8], lD = pp[9];
        cntle += (int)pp[10];
        if (hD >= hmax) { hmax = hD; imax = (int)pp[11]; }
        if (lD <= lmin) { lmin = lD; imin = (int)pp[12]; }
      }
      loadA(std::integral_constant<int, 60>{});    // c_ = close[T-60]
      EMITA(60, 58);                               // global 129..157
    } else if (role == 1) {                        // C0: pairs 11..30, emits; combine; w60
      unroll_for<11, 9>(stepC);
      pairC(std::integral_constant<int, 20>{});
      EMITC(20, 0);
      pv_c = c_; pv_v = v_;
      unroll_for<21, 9>(stepC);
      pairC(std::integral_constant<int, 30>{});
      EMITC(30, 29);
      sr += pp[13]; sr2 += pp[14];
      sl += pp[15]; sl2 += pp[16]; srl += pp[17];
      sw += pp[18]; sw2 += pp[19];
      sp += pp[20]; sn += pp[21];
      dvp += pp[22]; dvn += pp[23];
      npos += (int)pp[24]; nneg += (int)pp[25];
      EMITC(60, 58);
    } else if (role == 2) {                        // A1: w20 quantiles
      float t32[32];
      unroll_for<0, 32>([&](auto qi) {
        constexpr int i = decltype(qi)::value;
        t32[i] = (i < 20) ? cb[WMAX - i] : INFINITY;
      });
      bitonic_sort<32>(t32);
      QEMIT(20, 0, t32);
    } else if (role == 3) {                        // C1: e30 + merges + w60 quantiles
      float e30[32];
      unroll_for<0, 32>([&](auto qi) {
        constexpr int i = decltype(qi)::value;
        e30[i] = (i < 30) ? cb[WMAX - 30 - i] : INFINITY;
      });
      bitonic_sort<32>(e30);
      // ranks 11,12 of 60-union: merge heads s30[0..12] & e30[0..12]
      float hm[32];
      unroll_for<0, 16>([&](auto qi) {
        constexpr int i = decltype(qi)::value;
        hm[i] = (i < 13) ? s30r[i] : INFINITY;
      });
      unroll_for<0, 16>([&](auto qi) {
        constexpr int i = decltype(qi)::value;
        hm[16 + i] = (i < 3) ? INFINITY : e30[15 - i];   // descending half
      });
      bitonic_merge<32>(hm);
      float q11 = hm[11], q12 = hm[12];
      // ranks 47,48: merge tails s30[17..29] & e30[17..29]
      float tmm[32];
      unroll_for<0, 16>([&](auto qi) {
        constexpr int i = decltype(qi)::value;
        tmm[i] = (i < 13) ? s30r[17 + i] : INFINITY;
      });
      unroll_for<0, 16>([&](auto qi) {
        constexpr int i = decltype(qi)::value;
        tmm[16 + i] = (i < 3) ? INFINITY : e30[32 - i];  // descending half
      });
      bitonic_merge<32>(tmm);
      float q47 = tmm[13], q48 = tmm[14];
      {
        constexpr float f8_ = (float)(0.8 * 59 - (int)(0.8 * 59));
        constexpr float f2_ = (float)(0.2 * 59 - (int)(0.2 * 59));
        outr[58 + 8] = (q47 + f8_ * (q48 - q47)) * rcl;
        outr[58 + 9] = (q11 + f2_ * (q12 - q11)) * rcl;
      }
    } else {                                       // B: w30 quantiles from s30l
      constexpr int   k8_ = (int)(0.8 * 29);
      constexpr float f8_ = (float)(0.8 * 29 - k8_);
      constexpr int   k2_ = (int)(0.2 * 29);
      constexpr float f2_ = (float)(0.2 * 29 - k2_);
      float a8 = s30r[k8_], b8 = s30r[k8_ + 1];
      float a2 = s30r[k2_], b2 = s30r[k2_ + 1];
      outr[29 + 8] = (a8 + f8_ * (b8 - a8)) * rcl;
      outr[29 + 9] = (a2 + f2_ * (b2 - a2)) * rcl;
    }
  }
  __syncthreads();

  { // flush 2: features 71..157
    float* gout = out + ((size_t)b * LP + ch * CHUNK) * NF + PH1;
    for (int r = role; r < clen; r += NW) {
      const float* src = ob + r * OBW;
      float* dst = gout + (size_t)r * NF;
      for (int k = tt; k < OBW; k += 64) dst[k] = src[k];
    }
  }
}

extern "C" void kernel_launch(void* const* d_in, const int* in_sizes, int n_in,
                              void* d_out, int out_size, void* d_ws, size_t ws_size,
                              hipStream_t stream) {
  const float* x = (const float*)d_in[0];
  float* out = (float*)d_out;
  int B = in_sizes[0] / (LLEN * 6);   // 128
  dim3 grid(B * NCH), block(NT);
  hipLaunchKernelGGL(factor_kernel, grid, block, 0, stream, x, out, B);
}

// Round 14
// 33.737 us; speedup vs baseline: 1.7758x; 1.7758x over previous
//
#include <hip/hip_runtime.h>
#include <math.h>
#include <utility>

#define EPSF 1e-12f

constexpr int LLEN = 1024;
constexpr int WMAX = 60;
constexpr int LP   = 964;
constexpr int NF   = 158;
constexpr int CHUNK = 64;
constexpr int SPAN  = CHUNK + WMAX; // 124
constexpr int NCH   = (LP + CHUNK - 1) / CHUNK; // 16
constexpr int OBW   = 87;           // LDS row stride; 87%32=23 coprime w/ 32
constexpr int PH1   = 71;           // phase-1 width: base(13)+w5(29)+w10(29)
constexpr int NT    = 256;          // 4 waves: A(pass1) C(pass2) B1 B2

__device__ __forceinline__ float frcp(float x) {
#if __has_builtin(__builtin_amdgcn_rcpf)
  return __builtin_amdgcn_rcpf(x);
#else
  return 1.0f / x;
#endif
}

template<int I0, class F, int... Is>
__device__ __forceinline__ void unroll_impl(F&& f, std::integer_sequence<int, Is...>) {
  (f(std::integral_constant<int, I0 + Is>{}), ...);
}
template<int I0, int N, class F>
__device__ __forceinline__ void unroll_for(F&& f) {
  unroll_impl<I0>(f, std::make_integer_sequence<int, N>{});
}

template<int N>
__device__ __forceinline__ void bitonic_sort(float (&a)[N]) {
#pragma unroll
  for (int k = 2; k <= N; k <<= 1) {
#pragma unroll
    for (int j = k >> 1; j > 0; j >>= 1) {
#pragma unroll
      for (int i = 0; i < N; ++i) {
        int l = i ^ j;
        if (l > i) {
          float x = a[i], y = a[l];
          float mn = fminf(x, y), mx = fmaxf(x, y);
          if ((i & k) == 0) { a[i] = mn; a[l] = mx; }
          else              { a[i] = mx; a[l] = mn; }
        }
      }
    }
  }
}

// Ascending merge of a bitonic sequence (asc half ++ desc half).
template<int N>
__device__ __forceinline__ void bitonic_merge(float (&a)[N]) {
#pragma unroll
  for (int j = N >> 1; j > 0; j >>= 1) {
#pragma unroll
    for (int i = 0; i < N; ++i) {
      int l = i ^ j;
      if (l > i) {
        float x = a[i], y = a[l];
        a[i] = fminf(x, y); a[l] = fmaxf(x, y);
      }
    }
  }
}

// pass1 feature emit (slots 0-7,10-15,23,24); c_ is close[T-W_].
#define EMITA(W_, FI_) do {                                                   \
  constexpr float wf_  = (float)(W_);                                         \
  constexpr float inw_ = 1.0f / wf_;                                          \
  constexpr float tm_  = (W_ - 1) * 0.5f;                                     \
  constexpr float tv_  = (float)(((double)(W_) * (W_) - 1.0) / 12.0);         \
  float scm_  = sc * inw_;                                                    \
  float ym_   = cl + scm_;                                                    \
  float yvar_ = fmaxf(sc2 * inw_ - scm_ * scm_, 0.f);                         \
  float stdv_ = sqrtf(yvar_);                                                 \
  float skc_  = (wf_ - 1.f) * sc - sic;                                       \
  float cov_  = skc_ * inw_ - tm_ * scm_;                                     \
  float slope_ = cov_ * (1.0f / tv_);                                         \
  float rsqr_  = cov_ * cov_ * frcp(tv_ * yvar_ + EPSF);                      \
  float resi_  = (cl - ym_) - slope_ * tm_;                                   \
  float cnum_ = sclg - sc * slg * inw_;                                       \
  float cden_ = sqrtf(fmaxf(sc2 - sc * sc * inw_, 0.f) *                      \
                      fmaxf(slg2 - slg * slg * inw_, 0.f)) + EPSF;            \
  float corr_ = cnum_ * frcp(cden_);                                          \
  float vmean_ = sv * inw_;                                                   \
  float vvar_  = fmaxf(sv2 * inw_ - vmean_ * vmean_, 0.f);                    \
  float imaxf_ = (float)((W_ - 1) - imax) * inw_;                             \
  float iminf_ = (float)((W_ - 1) - imin) * inw_;                             \
  outr[FI_ + 0]  = c_ * rcl;                                                  \
  outr[FI_ + 1]  = ym_ * rcl;                                                 \
  outr[FI_ + 2]  = stdv_ * rcl;                                               \
  outr[FI_ + 3]  = slope_ * rcl;                                              \
  outr[FI_ + 4]  = rsqr_;                                                     \
  outr[FI_ + 5]  = resi_ * rcl;                                               \
  outr[FI_ + 6]  = hmax * rcl;                                                \
  outr[FI_ + 7]  = lmin * rcl;                                                \
  outr[FI_ + 10] = (float)cntle * inw_;                                       \
  outr[FI_ + 11] = (cl - lmin) * frcp(hmax - lmin + EPSF);                    \
  outr[FI_ + 12] = imaxf_;                                                    \
  outr[FI_ + 13] = iminf_;                                                    \
  outr[FI_ + 14] = imaxf_ - iminf_;                                           \
  outr[FI_ + 15] = corr_;                                                     \
  outr[FI_ + 23] = vmean_ * rvA;                                              \
  outr[FI_ + 24] = sqrtf(vvar_) * rvA;                                        \
} while (0)

// pass2 feature emit (slots 16-22,25-28).
#define EMITC(W_, FI_) do {                                                   \
  constexpr float inw_ = 1.0f / (float)(W_);                                  \
  float dnum_ = srl - sr * sl * inw_;                                         \
  float dden_ = sqrtf(fmaxf(sr2 - sr * sr * inw_, 0.f) *                      \
                      fmaxf(sl2 - sl * sl * inw_, 0.f)) + EPSF;               \
  float cord_ = dnum_ * frcp(dden_);                                          \
  float ra_ = frcp(sp + sn + EPSF);                                           \
  float sump_ = sp * ra_,  sumn_ = sn * ra_;                                  \
  float rv_ = frcp(dvp + dvn + EPSF);                                         \
  float vsump_ = dvp * rv_, vsumn_ = dvn * rv_;                               \
  float wmean_ = sw * inw_;                                                   \
  float wvar_  = fmaxf(sw2 * inw_ - wmean_ * wmean_, 0.f);                    \
  float cntp_ = (float)npos * inw_, cntn_ = (float)nneg * inw_;               \
  outr[FI_ + 16] = cord_;                                                     \
  outr[FI_ + 17] = cntp_;                                                     \
  outr[FI_ + 18] = cntn_;                                                     \
  outr[FI_ + 19] = cntp_ - cntn_;                                             \
  outr[FI_ + 20] = sump_;                                                     \
  outr[FI_ + 21] = sumn_;                                                     \
  outr[FI_ + 22] = sump_ - sumn_;                                             \
  outr[FI_ + 25] = sqrtf(wvar_) * frcp(wmean_ + EPSF);                        \
  outr[FI_ + 26] = vsump_;                                                    \
  outr[FI_ + 27] = vsumn_;                                                    \
  outr[FI_ + 28] = vsump_ - vsumn_;                                           \
} while (0)

// quantile emit from sorted array (jnp.quantile 'linear').
#define QEMIT(W_, FI_, TA_) do {                                              \
  constexpr int   k8_  = (int)(0.8 * (W_ - 1));                               \
  constexpr float f8_  = (float)(0.8 * (W_ - 1) - k8_);                       \
  constexpr int   k2_  = (int)(0.2 * (W_ - 1));                               \
  constexpr float f2_  = (float)(0.2 * (W_ - 1) - k2_);                       \
  outr[FI_ + 8] = (TA_[k8_] + f8_ * (TA_[k8_ + 1] - TA_[k8_])) * rcl;         \
  outr[FI_ + 9] = (TA_[k2_] + f2_ * (TA_[k2_ + 1] - TA_[k2_])) * rcl;         \
} while (0)

__global__ __launch_bounds__(NT, 4)
void factor_kernel(const float* __restrict__ x, float* __restrict__ out, int B)
{
  __shared__ float cs[SPAN], hs[SPAN], ls[SPAN], vs[SPAN], lgs[SPAN];   // 2480 B
  __shared__ float rr[SPAN], lc[SPAN], wvs[SPAN], dcs[SPAN], dvs[SPAN]; // 2480 B
  __shared__ float ob[CHUNK * OBW];   // 22272 B

  const int b    = blockIdx.x / NCH;
  const int ch   = blockIdx.x % NCH;
  const int t0   = WMAX + ch * CHUNK;
  const int clen = min(CHUNK, LP - ch * CHUNK);
  const int base = t0 - WMAX;
  const int span = clen + WMAX;
  const int tid  = threadIdx.x;
  const int tt   = tid & 63;
  const int role = tid >> 6;   // 0=A(pass1) 1=C(pass2) 2=B1(q5/10/20) 3=B2(q30/60)

  // stage raw series
  for (int u = tid; u < span; u += NT) {
    const float* p = x + (size_t)(b * LLEN + base + u) * 6;
    float hv = p[1], lv = p[2], cv = p[3], vv = p[4];
    cs[u] = cv; hs[u] = hv; ls[u] = lv; vs[u] = vv;
    lgs[u] = logf(vv + 1.f);
  }
  __syncthreads();
  // stage derived pair-series (depend only on pair index, shared by all T)
  for (int u = tid; u < span - 1; u += NT) {
    float c0 = cs[u], c1 = cs[u + 1];
    float v0 = vs[u], v1 = vs[u + 1];
    float r = c1 * frcp(c0) - 1.f;
    rr[u]  = r;
    dcs[u] = c1 - c0;
    dvs[u] = v1 - v0;
    lc[u]  = __logf(v1 * frcp(v0 + EPSF) + 1.f);
    wvs[u] = fabsf(r) * v1;
  }
  __syncthreads();

  const bool active = (tt < clen);
  const int tg = t0 + tt;

  const float* cb  = cs  + tt;   // cb[WMAX - i] == series[T - i]
  const float* hb  = hs  + tt;
  const float* lb  = ls  + tt;
  const float* vb  = vs  + tt;
  const float* gb  = lgs + tt;
  const float* rrb = rr  + tt;   // rrb[WMAX - i] == pair value for pair i
  const float* lcb = lc  + tt;
  const float* wvb = wvs + tt;
  const float* dcb = dcs + tt;
  const float* dvb = dvs + tt;

  const float cl  = cb[WMAX];
  const float vol = vb[WMAX];
  const float lgT = gb[WMAX];
  const float rcl = 1.0f / cl;
  const float rvA = 1.0f / (vol + EPSF);

  float* outr = ob + tt * OBW;

  // scan state (role-specific subsets; persists across barriers)
  float sc = 0.f, sc2 = 0.f, sic = 0.f;
  float sv = 0.f, sv2 = 0.f;
  float slg = 0.f, slg2 = 0.f, sclg = 0.f;
  int   cntle = 0;
  float hmax = -INFINITY, lmin = INFINITY;
  int   imax = 0, imin = 0;
  float sr = 0.f, sr2 = 0.f, sl = 0.f, sl2 = 0.f, srl = 0.f;
  float sw = 0.f, sw2 = 0.f;
  float sp = 0.f, sn = 0.f, dvp = 0.f, dvn = 0.f;
  int   npos = 0, nneg = 0;
  float c_ = 0.f, h_ = 0.f, l_ = 0.f, v_ = 0.f, lg_ = 0.f;
  float s30[32];               // B2's sorted low-half (persists ph1 -> ph2)

  auto loadA = [&](auto ic) {
    constexpr int i = decltype(ic)::value;
    constexpr int q = WMAX - i;
    c_ = cb[q];
    if constexpr (i < WMAX) { h_ = hb[q]; l_ = lb[q]; v_ = vb[q]; lg_ = gb[q]; }
  };
  auto p1A = [&](auto ic) {
    constexpr int i = decltype(ic)::value;
    float cd = c_ - cl;
    sc += cd; sc2 = fmaf(cd, cd, sc2); sic = fmaf((float)i, cd, sic);
    cntle += (c_ <= cl) ? 1 : 0;
    if (h_ >= hmax) { hmax = h_; imax = i; }
    if (l_ <= lmin) { lmin = l_; imin = i; }
    sv += v_; sv2 = fmaf(v_, v_, sv2);
    float ld = lg_ - lgT;
    slg += ld; slg2 = fmaf(ld, ld, slg2); sclg = fmaf(cd, ld, sclg);
  };
  auto stepA = [&](auto ic) { loadA(ic); p1A(ic); };

  // pass2 pair i from staged series (i >= 1)
  auto pairS = [&](auto ic) {
    constexpr int i = decltype(ic)::value;
    constexpr int q = WMAX - i;
    float r   = rrb[q];
    float lcv = lcb[q];
    float wvv = wvb[q];
    float d   = dcb[q];
    float dv  = dvb[q];
    sr += r;   sr2 = fmaf(r, r, sr2);
    sl += lcv; sl2 = fmaf(lcv, lcv, sl2); srl = fmaf(r, lcv, srl);
    sw += wvv; sw2 = fmaf(wvv, wvv, sw2);
    npos += (d > 0.f) ? 1 : 0;
    nneg += (d < 0.f) ? 1 : 0;
    sp  += fmaxf(d, 0.f);  sn  += fmaxf(-d, 0.f);
    dvp += fmaxf(dv, 0.f); dvn += fmaxf(-dv, 0.f);
  };

  // ================= phase 1 (features 0..70) =================
  if (active) {
    if (role == 0) {                               // A: base + pass1 i=0..10
      const float* p = x + (size_t)(b * LLEN + tg) * 6;
      float opn = p[0], vwp = p[5];
      float hi = hb[WMAX], lo = lb[WMAX];
      float hl = hi - lo + EPSF;
      float rhl = frcp(hl);
      float ro  = 1.0f / opn;
      float mx_oc = fmaxf(opn, cl), mn_oc = fminf(opn, cl);
      float body2 = 2.f * cl - hi - lo;
      outr[0]  = (cl - opn) * ro;
      outr[1]  = (hi - lo) * ro;
      outr[2]  = (cl - opn) * rhl;
      outr[3]  = (hi - mx_oc) * ro;
      outr[4]  = (hi - mx_oc) * rhl;
      outr[5]  = (mn_oc - lo) * ro;
      outr[6]  = (mn_oc - lo) * rhl;
      outr[7]  = body2 * ro;
      outr[8]  = body2 * rhl;
      outr[9]  = opn * rcl;
      outr[10] = hi * rcl;
      outr[11] = lo * rcl;
      outr[12] = vwp * rcl;

      unroll_for<0, 5>(stepA);                     // i = 0..4
      loadA(std::integral_constant<int, 5>{});
      EMITA(5, 13);
      p1A(std::integral_constant<int, 5>{});
      unroll_for<6, 4>(stepA);                     // i = 6..9
      loadA(std::integral_constant<int, 10>{});
      EMITA(10, 42);
      p1A(std::integral_constant<int, 10>{});
    } else if (role == 1) {                        // C: pairs 1..10 from staged
      unroll_for<1, 5>(pairS);                     // pairs 1..5
      EMITC(5, 13);
      unroll_for<6, 5>(pairS);                     // pairs 6..10
      EMITC(10, 42);
    } else if (role == 2) {                        // B1: q5 + q10
      float t8[8];
      unroll_for<0, 8>([&](auto qi) {
        constexpr int i = decltype(qi)::value;
        t8[i] = (i < 5) ? cb[WMAX - i] : INFINITY;
      });
      bitonic_sort<8>(t8);
      QEMIT(5, 13, t8);
      float t16[16];
      unroll_for<0, 16>([&](auto qi) {
        constexpr int i = decltype(qi)::value;
        t16[i] = (i < 10) ? cb[WMAX - i] : INFINITY;
      });
      bitonic_sort<16>(t16);
      QEMIT(10, 42, t16);
    } else {                                       // B2: sort low half (i=0..29)
      unroll_for<0, 32>([&](auto qi) {
        constexpr int i = decltype(qi)::value;
        s30[i] = (i < 30) ? cb[WMAX - i] : INFINITY;
      });
      bitonic_sort<32>(s30);
    }
  }
  __syncthreads();

  { // flush 1: features 0..70
    float* gout = out + ((size_t)b * LP + ch * CHUNK) * NF;
    const int total = clen * PH1;
    for (int n = tid; n < total; n += NT) {
      int r = n / PH1, cc = n - r * PH1;
      gout[(size_t)r * NF + cc] = ob[r * OBW + cc];
    }
  }
  __syncthreads();

  // ================= phase 2 (features 71..157) =================
  if (active) {
    if (role == 0) {                               // A: i=11..59, emits w20,w30,w60
      unroll_for<11, 9>(stepA);
      loadA(std::integral_constant<int, 20>{});
      EMITA(20, 0);                                // global 71..99
      p1A(std::integral_constant<int, 20>{});
      unroll_for<21, 9>(stepA);
      loadA(std::integral_constant<int, 30>{});
      EMITA(30, 29);                               // global 100..128
      p1A(std::integral_constant<int, 30>{});
      unroll_for<31, 29>(stepA);                   // i = 31..59
      loadA(std::integral_constant<int, 60>{});
      EMITA(60, 58);                               // global 129..157
    } else if (role == 1) {                        // C: pairs 11..60
      unroll_for<11, 10>(pairS);                   // pairs 11..20
      EMITC(20, 0);
      unroll_for<21, 10>(pairS);                   // pairs 21..30
      EMITC(30, 29);
      unroll_for<31, 30>(pairS);                   // pairs 31..60
      EMITC(60, 58);
    } else if (role == 2) {                        // B1: q20
      float t32[32];
      unroll_for<0, 32>([&](auto qi) {
        constexpr int i = decltype(qi)::value;
        t32[i] = (i < 20) ? cb[WMAX - i] : INFINITY;
      });
      bitonic_sort<32>(t32);
      QEMIT(20, 0, t32);
    } else {                                       // B2: q30 + e30 + merges + q60
      QEMIT(30, 29, s30);                          // from persisted sorted regs
      float e30[32];                               // high half (i=30..59)
      unroll_for<0, 32>([&](auto qi) {
        constexpr int i = decltype(qi)::value;
        e30[i] = (i < 30) ? cb[WMAX - 30 - i] : INFINITY;
      });
      bitonic_sort<32>(e30);
      // ranks 11,12 of 60-union: merge heads s30[0..12] & e30[0..12]
      float hm[32];
      unroll_for<0, 16>([&](auto qi) {
        constexpr int i = decltype(qi)::value;
        hm[i] = (i < 13) ? s30[i] : INFINITY;
      });
      unroll_for<0, 16>([&](auto qi) {
        constexpr int i = decltype(qi)::value;
        hm[16 + i] = (i < 3) ? INFINITY : e30[15 - i];   // descending half
      });
      bitonic_merge<32>(hm);
      float q11 = hm[11], q12 = hm[12];
      // ranks 47,48: merge tails s30[17..29] & e30[17..29]
      float tmm[32];
      unroll_for<0, 16>([&](auto qi) {
        constexpr int i = decltype(qi)::value;
        tmm[i] = (i < 13) ? s30[17 + i] : INFINITY;
      });
      unroll_for<0, 16>([&](auto qi) {
        constexpr int i = decltype(qi)::value;
        tmm[16 + i] = (i < 3) ? INFINITY : e30[32 - i];  // descending half
      });
      bitonic_merge<32>(tmm);
      float q47 = tmm[13], q48 = tmm[14];
      {
        constexpr float f8_ = (float)(0.8 * 59 - (int)(0.8 * 59));
        constexpr float f2_ = (float)(0.2 * 59 - (int)(0.2 * 59));
        outr[58 + 8] = (q47 + f8_ * (q48 - q47)) * rcl;
        outr[58 + 9] = (q11 + f2_ * (q12 - q11)) * rcl;
      }
    }
  }
  __syncthreads();

  { // flush 2: features 71..157
    float* gout = out + ((size_t)b * LP + ch * CHUNK) * NF + PH1;
    const int total = clen * OBW;
    for (int n = tid; n < total; n += NT) {
      int r = n / OBW, cc = n - r * OBW;
      gout[(size_t)r * NF + cc] = ob[n];
    }
  }
}

extern "C" void kernel_launch(void* const* d_in, const int* in_sizes, int n_in,
                              void* d_out, int out_size, void* d_ws, size_t ws_size,
                              hipStream_t stream) {
  const float* x = (const float*)d_in[0];
  float* out = (float*)d_out;
  int B = in_sizes[0] / (LLEN * 6);   // 128
  dim3 grid(B * NCH), block(NT);
  hipLaunchKernelGGL(factor_kernel, grid, block, 0, stream, x, out, B);
}